// Round 8
// baseline (2442.175 us; speedup 1.0000x reference)
//
#include <hip/hip_runtime.h>

// T=256, B=512, D=256, H=512, 4H=2048, K=768 fused ([x|h] @ [W_ih|W_hh]^T)
// Persistent kernel: 256 blocks (1/CU via ~102KB LDS), 256 threads (4 waves).
// Block (mt=bid&7, nt=bid>>3): batch rows mt*64..+63, h-cols nt*16..+15.
// W resident in LDS (96KB f16, gate-interleaved, XOR swizzle). Sync:
// per-producer-WAVE flag words (sc0 sc1 stores), consumers poll 32 flag
// quads (sc0 sc1). h in a write-once history buffer hs[t] (producers store
// sc0 sc1 write-through; consumers load PLAIN cacheable).
//
// ROUND 8 (single-variable reorder on the proven 1594us kernel):
//   gemm_x is split. kc0..3 + attn run BEFORE wait_flags (cover flag
//   propagation, as before); after flags are observed the 16 h loads + 2
//   attn loads are issued FIRST, then kc4..7 x-MFMAs run while they fly.
//   This moves ~0.4us of compute under the previously fully-exposed h-load
//   IC latency. All wait conditions/counts and the flag protocol are
//   byte-identical to the proven kernel; risk is perf-only.

typedef _Float16 f16x8 __attribute__((ext_vector_type(8)));
typedef short    s16x8 __attribute__((ext_vector_type(8)));
typedef float    f32x4 __attribute__((ext_vector_type(4)));

union F16U { f16x8 v; _Float16 e[8]; };

__device__ __forceinline__ float h2f(unsigned short b) {
    return (float)__builtin_bit_cast(_Float16, b);
}
__device__ __forceinline__ unsigned short f2h(float f) {
    return __builtin_bit_cast(unsigned short, (_Float16)f);
}
__device__ __forceinline__ float sigf(float x) { return 1.0f / (1.0f + __expf(-x)); }
__device__ __forceinline__ float tanh_(float x) {
    float e = __expf(-2.0f * fabsf(x));
    float r = (1.0f - e) / (1.0f + e);
    return x < 0.0f ? -r : r;
}
__device__ __forceinline__ unsigned umin_(unsigned a, unsigned b) { return a < b ? a : b; }

__device__ __forceinline__ f16x8 loadA32(const float* p) {
    float4 a = *(const float4*)p, b = *(const float4*)(p + 4);
    F16U r;
    r.e[0]=(_Float16)a.x; r.e[1]=(_Float16)a.y; r.e[2]=(_Float16)a.z; r.e[3]=(_Float16)a.w;
    r.e[4]=(_Float16)b.x; r.e[5]=(_Float16)b.y; r.e[6]=(_Float16)b.z; r.e[7]=(_Float16)b.w;
    return r.v;
}

#define MFMA16(a, b, c) __builtin_amdgcn_mfma_f32_16x16x32_f16((a), (b), (c), 0, 0, 0)
#define BIDX(g, kc)  (((g) * 16 + lj) * 96 + ((((kc) * 4) + lq) ^ vg[(g)]))

// Issue 16 x-loads for 16 rows x full K=256 (fire-and-forget).
__device__ __forceinline__ void issue_x(const float* x_t, int arow, int lq, float4* xpf) {
    const float* xb = x_t + (size_t)arow * 256 + lq * 8;
#pragma unroll
    for (int i = 0; i < 8; ++i) {
        asm volatile("global_load_dwordx4 %0, %1, off offset:%c2"
                     : "=v"(xpf[2 * i]) : "v"(xb), "i"(i * 128));
        asm volatile("global_load_dwordx4 %0, %1, off offset:%c2"
                     : "=v"(xpf[2 * i + 1]) : "v"(xb), "i"(i * 128 + 16));
    }
}

// x-part of gates GEMM, kc = KC0..KC1-1 (x regs must already be drained).
template<int KC0, int KC1>
__device__ __forceinline__ void gemm_x_part(const float4* xpf, const f16x8* Wl,
    int lj, int lq, const int* vg,
    f32x4& acc0, f32x4& acc1, f32x4& acc2, f32x4& acc3)
{
#pragma unroll
    for (int kc = KC0; kc < KC1; ++kc) {
        float4 a = xpf[2 * kc], b = xpf[2 * kc + 1];
        F16U r;
        r.e[0]=(_Float16)a.x; r.e[1]=(_Float16)a.y; r.e[2]=(_Float16)a.z; r.e[3]=(_Float16)a.w;
        r.e[4]=(_Float16)b.x; r.e[5]=(_Float16)b.y; r.e[6]=(_Float16)b.z; r.e[7]=(_Float16)b.w;
        acc0 = MFMA16(r.v, Wl[BIDX(0, kc)], acc0);
        acc1 = MFMA16(r.v, Wl[BIDX(1, kc)], acc1);
        acc2 = MFMA16(r.v, Wl[BIDX(2, kc)], acc2);
        acc3 = MFMA16(r.v, Wl[BIDX(3, kc)], acc3);
    }
}

// Poll group's 32 producer blocks (4 wave-flags each). sc0 sc1 REQUIRED.
__device__ __forceinline__ void wait_flags(const uint4* fbase, int l, unsigned target) {
    if (l < 32) {
        const uint4* p = fbase + l;
        unsigned m;
        do {
            uint4 v;
            asm volatile("global_load_dwordx4 %0, %1, off sc0 sc1" : "=v"(v) : "v"(p));
            asm volatile("s_waitcnt vmcnt(0)" ::: "memory");
            m = umin_(umin_(v.x, v.y), umin_(v.z, v.w));
        } while (m < target);
    }
    __builtin_amdgcn_sched_barrier(0);
}

// h-part of gates GEMM with x-second-half overlap. Issues the 16 h loads +
// 2 attn loads FIRST (outstanding must be 0 on entry), then runs x kc4..7
// MFMAs while they fly, then the staged h waits/MFMAs (same counts as the
// proven kernel). hdot/hctx left in flight (retired by epilogue vmcnt(16)).
__device__ __forceinline__ void gemm_h_ov(const unsigned short* hsrc, const f16x8* Wl,
    int arow, int lj, int lq, const int* vg,
    const unsigned short* ap_dot, const unsigned short* ap_ctx,
    uint4& hdot, uint2& hctx, const float4* xpf,
    f32x4& acc0, f32x4& acc1, f32x4& acc2, f32x4& acc3)
{
    const unsigned short* hp = hsrc + (size_t)arow * 512 + lq * 8;
    s16x8 hf[16];
#pragma unroll
    for (int i = 0; i < 16; ++i)
        asm volatile("global_load_dwordx4 %0, %1, off offset:%c2"
                     : "=v"(hf[i]) : "v"(hp), "i"(i * 64));
    asm volatile("global_load_dwordx4 %0, %1, off" : "=v"(hdot) : "v"(ap_dot));
    asm volatile("global_load_dwordx2 %0, %1, off" : "=v"(hctx) : "v"(ap_ctx));
    __builtin_amdgcn_sched_barrier(0);   // pin: loads issued before x-MFMAs

    // x second half overlaps the h-load flight (x regs drained earlier)
    gemm_x_part<4, 8>(xpf, Wl, lj, lq, vg, acc0, acc1, acc2, acc3);

    asm volatile("s_waitcnt vmcnt(10)" ::: "memory");   // hf[0..7] ready
    __builtin_amdgcn_sched_barrier(0);
#pragma unroll
    for (int kc = 8; kc < 16; ++kc) {
        f16x8 a = __builtin_bit_cast(f16x8, hf[kc - 8]);
        acc0 = MFMA16(a, Wl[BIDX(0, kc)], acc0);
        acc1 = MFMA16(a, Wl[BIDX(1, kc)], acc1);
        acc2 = MFMA16(a, Wl[BIDX(2, kc)], acc2);
        acc3 = MFMA16(a, Wl[BIDX(3, kc)], acc3);
    }
    asm volatile("s_waitcnt vmcnt(2)" ::: "memory");    // hf[8..15] ready
    __builtin_amdgcn_sched_barrier(0);
#pragma unroll
    for (int kc = 16; kc < 24; ++kc) {
        f16x8 a = __builtin_bit_cast(f16x8, hf[kc - 8]);
        acc0 = MFMA16(a, Wl[BIDX(0, kc)], acc0);
        acc1 = MFMA16(a, Wl[BIDX(1, kc)], acc1);
        acc2 = MFMA16(a, Wl[BIDX(2, kc)], acc2);
        acc3 = MFMA16(a, Wl[BIDX(3, kc)], acc3);
    }
    // hdot/hctx intentionally left in flight.
}

// h-part from fp32 hidden_init (t=0 only).
__device__ __forceinline__ void gemm_h_init_fb(const float* hsrc, const f16x8* Wl,
    int arow, int lj, int lq, const int* vg,
    f32x4& acc0, f32x4& acc1, f32x4& acc2, f32x4& acc3)
{
    const float* hb = hsrc + (size_t)arow * 512 + lq * 8;
#pragma unroll
    for (int kc = 8; kc < 24; ++kc) {
        f16x8 a = loadA32(hb + (kc - 8) * 32);
        acc0 = MFMA16(a, Wl[BIDX(0, kc)], acc0);
        acc1 = MFMA16(a, Wl[BIDX(1, kc)], acc1);
        acc2 = MFMA16(a, Wl[BIDX(2, kc)], acc2);
        acc3 = MFMA16(a, Wl[BIDX(3, kc)], acc3);
    }
}

// Pure-register online-softmax update: each wave owns one attention row
// (row = attr0 + (w>>1)); computes the FULL 512-dot redundantly per wave
// and updates its 4 ctx cols (cols (w&1)*256 + l*4). No LDS, no barriers.
__device__ __forceinline__ void attn_apply(uint4 hd, uint2 hc, const float* wv8,
    float s_bias, float& m_r, float& l_r, float ctx[4])
{
    float p = h2f((unsigned short)(hd.x & 0xffffu)) * wv8[0]
            + h2f((unsigned short)(hd.x >> 16))     * wv8[1]
            + h2f((unsigned short)(hd.y & 0xffffu)) * wv8[2]
            + h2f((unsigned short)(hd.y >> 16))     * wv8[3]
            + h2f((unsigned short)(hd.z & 0xffffu)) * wv8[4]
            + h2f((unsigned short)(hd.z >> 16))     * wv8[5]
            + h2f((unsigned short)(hd.w & 0xffffu)) * wv8[6]
            + h2f((unsigned short)(hd.w >> 16))     * wv8[7];
#pragma unroll
    for (int off = 32; off > 0; off >>= 1) p += __shfl_xor(p, off);
    float s = p + s_bias;
    float m_new = fmaxf(m_r, s);
    float scale = __expf(m_r - m_new);   // exp(-inf)=0 on first update
    float pr    = __expf(s - m_new);
    ctx[0] = ctx[0] * scale + pr * h2f((unsigned short)(hc.x & 0xffffu));
    ctx[1] = ctx[1] * scale + pr * h2f((unsigned short)(hc.x >> 16));
    ctx[2] = ctx[2] * scale + pr * h2f((unsigned short)(hc.y & 0xffffu));
    ctx[3] = ctx[3] * scale + pr * h2f((unsigned short)(hc.y >> 16));
    l_r = l_r * scale + pr;
    m_r = m_new;
}

#define SMEM_FB 104192

__global__ __launch_bounds__(256, 1) void lstm_hist(
    const float* __restrict__ xg,
    const float* __restrict__ hinit, const float* __restrict__ cinit,
    const float* __restrict__ W_ih, const float* __restrict__ W_hh,
    const float* __restrict__ b_ih, const float* __restrict__ b_hh,
    const float* __restrict__ attn_w, const float* __restrict__ attn_b,
    const float* __restrict__ W1, const float* __restrict__ b1,
    const float* __restrict__ W2, const float* __restrict__ b2,
    const float* __restrict__ W3, const float* __restrict__ b3,
    const float* __restrict__ W4, const float* __restrict__ b4,
    float* __restrict__ out,
    unsigned short* __restrict__ hbA, unsigned* __restrict__ flags)
{
    extern __shared__ char smem[];
    f16x8* Wl    = (f16x8*)smem;
    float* bsum  = (float*)(smem + 98304);
    float* xmlp  = (float*)(smem + 98304 + 512);
    float* x1s   = xmlp + 1024;
    float* x2s   = x1s + 128;
    float* x3s   = x2s + 128;

    const int tid = threadIdx.x, bid = blockIdx.x;
    const int mt = bid & 7, nt = bid >> 3;
    const int hc0 = nt * 16;
    const int w = tid >> 6, l = tid & 63;
    const int lj = l & 15, lq = l >> 4;

    int vg[4];
#pragma unroll
    for (int g = 0; g < 4; ++g) {
        int q = g * 16 + lj;
        vg[g] = ((q >> 3) ^ q) & 7;
    }

    // ---- stage W into LDS (f16, gate-interleaved, row-dependent XOR swizzle) ----
    {
        int q = tid >> 2, si = tid & 3;
        int vq = ((q >> 3) ^ q) & 7;
        int grow = (q >> 4) * 512 + hc0 + (q & 15);
        const float* ih = W_ih + (size_t)grow * 256;
        const float* hh = W_hh + (size_t)grow * 512;
        for (int cc = 0; cc < 24; ++cc) {
            int s = si * 24 + cc;
            int k0 = s * 8;
            const float* p = (k0 < 256) ? (ih + k0) : (hh + (k0 - 256));
            Wl[q * 96 + (s ^ vq)] = loadA32(p);
        }
        if (tid < 64) {
            int gr = (tid >> 4) * 512 + hc0 + (tid & 15);
            bsum[tid] = b_ih[gr] + b_hh[gr];
        }
    }
    __syncthreads();

    const int arow = mt * 64 + w * 16 + lj;
    const int crow = mt * 64 + w * 16 + lq * 4;
    const int ccol = hc0 + lj;
    float creg[4];
#pragma unroll
    for (int r = 0; r < 4; ++r)
        creg[r] = cinit[(size_t)(crow + r) * 512 + ccol];

    // attention state: thread-private (redundant per wave-pair, consistent)
    float m_r = -__builtin_inff(), l_r = 0.f;
    float ctx[4] = {0.f, 0.f, 0.f, 0.f};
    uint4 hdot = {0, 0, 0, 0}; uint2 hctx = {0, 0};
    const int attr0 = mt * 64 + nt * 2;
    const int arow_at = attr0 + (w >> 1);
    const float s_bias = attn_b[0];
    float wv8[8];
    {
        float4 a = *(const float4*)(attn_w + l * 8);
        float4 b = *(const float4*)(attn_w + l * 8 + 4);
        wv8[0]=a.x; wv8[1]=a.y; wv8[2]=a.z; wv8[3]=a.w;
        wv8[4]=b.x; wv8[5]=b.y; wv8[6]=b.z; wv8[7]=b.w;
    }
    float bs0 = bsum[lj], bs1 = bsum[16 + lj], bs2 = bsum[32 + lj], bs3 = bsum[48 + lj];

    const size_t aoff_dot = (size_t)arow_at * 512 + l * 8;
    const size_t aoff_ctx = (size_t)arow_at * 512 + (w & 1) * 256 + l * 4;
    const uint4* fbase = (const uint4*)flags + mt * 32;
    unsigned* myflag = flags + (size_t)(mt * 32 + nt) * 4 + w;

    float4 xpf[16];
    issue_x(xg, arow, lq, xpf);

    for (int t = 0; t < 256; ++t) {
        unsigned short* hb_cur = hbA + (size_t)t * 262144;
        const unsigned short* hb_prev = hb_cur - 262144;

        f32x4 acc0 = {0,0,0,0}, acc1 = {0,0,0,0}, acc2 = {0,0,0,0}, acc3 = {0,0,0,0};

        // x regs ready (prefetched last step); nothing else outstanding
        asm volatile("s_waitcnt vmcnt(0)" ::: "memory");
        __builtin_amdgcn_sched_barrier(0);

        if (t > 0) {
            // first half of x-GEMM + attn cover the flag propagation window
            gemm_x_part<0, 4>(xpf, Wl, lj, lq, vg, acc0, acc1, acc2, acc3);
            if (t >= 2) attn_apply(hdot, hctx, wv8, s_bias, m_r, l_r, ctx);
            wait_flags(fbase, l, (unsigned)t);
            // h/attn loads issued first, x second half overlaps their flight
            gemm_h_ov(hb_prev, Wl, arow, lj, lq, vg,
                      hb_prev + aoff_dot, hb_prev + aoff_ctx, hdot, hctx, xpf,
                      acc0, acc1, acc2, acc3);
        } else {
            gemm_x_part<0, 8>(xpf, Wl, lj, lq, vg, acc0, acc1, acc2, acc3);
            gemm_h_init_fb(hinit, Wl, arow, lj, lq, vg, acc0, acc1, acc2, acc3);
        }

#pragma unroll
        for (int r = 0; r < 4; ++r) {
            float ii = sigf(acc0[r] + bs0);
            float ff = sigf(acc1[r] + bs1);
            float gt = tanh_(acc2[r] + bs2);
            float oo = sigf(acc3[r] + bs3);
            float cn = ff * creg[r] + ii * gt;
            creg[r] = cn;
            float hv = oo * tanh_(cn);
            size_t off = (size_t)(crow + r) * 512 + ccol;
            unsigned short hvs = f2h(hv);
            unsigned short* sp = hb_cur + off;
            asm volatile("global_store_short %0, %1, off sc0 sc1"
                         :: "v"(sp), "v"(hvs) : "memory");
            if (t == 255) out[512 + off] = hv;
        }

        const float* xnext = xg + (size_t)(t < 255 ? t + 1 : 255) * 131072;
        issue_x(xnext, arow, lq, xpf);

        // drain h stores (+ attn loads); 16 x loads stay in flight
        asm volatile("s_waitcnt vmcnt(16)" ::: "memory");
        if (l == 0) {
            unsigned fv = (unsigned)(t + 1);
            asm volatile("global_store_dword %0, %1, off sc0 sc1"
                         :: "v"(myflag), "v"(fv) : "memory");
        }
    }

    attn_apply(hdot, hctx, wv8, s_bias, m_r, l_r, ctx);
    wait_flags(fbase, l, 256u);
    {
        const unsigned short* hlast = hbA + (size_t)255 * 262144;
        const unsigned short* hp = hlast + aoff_dot;
        const unsigned short* hc = hlast + aoff_ctx;
        asm volatile("global_load_dwordx4 %0, %1, off" : "=v"(hdot) : "v"(hp));
        asm volatile("global_load_dwordx2 %0, %1, off" : "=v"(hctx) : "v"(hc));
        asm volatile("s_waitcnt vmcnt(0)" ::: "memory");
        __builtin_amdgcn_sched_barrier(0);
        attn_apply(hdot, hctx, wv8, s_bias, m_r, l_r, ctx);
    }

    // cT copyout
#pragma unroll
    for (int r = 0; r < 4; ++r)
        out[512 + 262144 + (size_t)(crow + r) * 512 + ccol] = creg[r];

    // ---- fused output MLP for this block's 2 batch rows ----
    {
        float linv = 1.0f / l_r;
        int row = tid >> 7, coff = (tid & 127) * 4;
#pragma unroll
        for (int i = 0; i < 4; ++i) xmlp[row * 512 + coff + i] = ctx[i] * linv;
    }
    __syncthreads();
    if (tid < 128) {
        int r = tid >> 6, f = tid & 63;
        const float* wp = W1 + (size_t)f * 512;
        const float* xp = xmlp + r * 512;
        float a = b1[f];
        for (int j = 0; j < 512; ++j) a = fmaf(xp[j], wp[j], a);
        x1s[r * 64 + f] = tanh_(a);
    }
    __syncthreads();
    if (tid < 128) {
        int r = tid >> 6, f = tid & 63;
        const float* wp = W2 + f * 64;
        const float* xp = x1s + r * 64;
        float a = b2[f];
        for (int j = 0; j < 64; ++j) a = fmaf(xp[j], wp[j], a);
        x2s[r * 64 + f] = tanh_(a);
    }
    __syncthreads();
    if (tid < 64) {
        int r = tid >> 5, f = tid & 31;
        const float* wp = W3 + f * 64;
        const float* xp = x2s + r * 64;
        float a = b3[f];
        for (int j = 0; j < 64; ++j) a = fmaf(xp[j], wp[j], a);
        x3s[r * 32 + f] = tanh_(a);
    }
    __syncthreads();
    if (tid < 2) {
        const float* xp = x3s + tid * 32;
        float a = b4[0];
        for (int j = 0; j < 32; ++j) a = fmaf(xp[j], W4[j], a);
        out[attr0 + tid] = a;
    }
}

extern "C" void kernel_launch(void* const* d_in, const int* in_sizes, int n_in,
                              void* d_out, int out_size, void* d_ws, size_t ws_size,
                              hipStream_t stream) {
    const float* xg     = (const float*)d_in[0];
    const float* hinit  = (const float*)d_in[1];
    const float* cinit  = (const float*)d_in[2];
    const float* W_ih   = (const float*)d_in[3];
    const float* W_hh   = (const float*)d_in[4];
    const float* b_ih   = (const float*)d_in[5];
    const float* b_hh   = (const float*)d_in[6];
    const float* attn_w = (const float*)d_in[7];
    const float* attn_b = (const float*)d_in[8];
    const float* W1 = (const float*)d_in[9],  *b1 = (const float*)d_in[10];
    const float* W2 = (const float*)d_in[11], *b2 = (const float*)d_in[12];
    const float* W3 = (const float*)d_in[13], *b3 = (const float*)d_in[14];
    const float* W4 = (const float*)d_in[15], *b4 = (const float*)d_in[16];

    const size_t HS_BYTES = 134217728ull;   // 256*512*512 f16 history

    unsigned short* hs = (unsigned short*)d_ws;
    unsigned* flags = (unsigned*)((char*)d_ws + HS_BYTES);
    hipMemsetAsync(flags, 0, 4096, stream);
    hipFuncSetAttribute((const void*)lstm_hist,
                        hipFuncAttributeMaxDynamicSharedMemorySize, SMEM_FB);
    lstm_hist<<<256, 256, SMEM_FB, stream>>>(
        xg, hinit, cinit, W_ih, W_hh, b_ih, b_hh, attn_w, attn_b,
        W1, b1, W2, b2, W3, b3, W4, b4,
        (float*)d_out, hs, flags);
}

// Round 9
// 1581.365 us; speedup vs baseline: 1.5443x; 1.5443x over previous
//
#include <hip/hip_runtime.h>

// T=256, B=512, D=256, H=512, 4H=2048, K=768 fused ([x|h] @ [W_ih|W_hh]^T)
// Persistent kernel: 256 blocks (1/CU via ~102KB LDS), 256 threads (4 waves).
// Block (mt=bid&7, nt=bid>>3): batch rows mt*64..+63, h-cols nt*16..+15.
// W resident in LDS (96KB f16, gate-interleaved, XOR swizzle). Sync:
// per-producer-WAVE flag words (plain sc0 sc1 stores), consumers poll 32
// flags in parallel (sc0 sc1). h in a write-once history buffer hs[t]
// (producers store sc0 sc1 write-through; consumers load PLAIN cacheable —
// a write-once line observed only after the flag cannot be stale).
//
// FINAL: byte-exact session-best kernel (measured 1594.6us, reproduced
// 1609-1668us across four runs). Latency-bound on the cross-block h handoff;
// six perturbations of this structure (coherence scope, gates precompute,
// W-in-VGPR x2, x-f16 pre-pass + pre-poll, compute reorder) all regressed
// or aborted — the last via VGPR 136->192 liveness growth breaking the
// compiler schedule. This source is the measured optimum of the session.

typedef _Float16 f16x8 __attribute__((ext_vector_type(8)));
typedef short    s16x8 __attribute__((ext_vector_type(8)));
typedef float    f32x4 __attribute__((ext_vector_type(4)));

union F16U { f16x8 v; _Float16 e[8]; };

__device__ __forceinline__ float h2f(unsigned short b) {
    return (float)__builtin_bit_cast(_Float16, b);
}
__device__ __forceinline__ unsigned short f2h(float f) {
    return __builtin_bit_cast(unsigned short, (_Float16)f);
}
__device__ __forceinline__ float sigf(float x) { return 1.0f / (1.0f + __expf(-x)); }
__device__ __forceinline__ float tanh_(float x) {
    float e = __expf(-2.0f * fabsf(x));
    float r = (1.0f - e) / (1.0f + e);
    return x < 0.0f ? -r : r;
}
__device__ __forceinline__ unsigned umin_(unsigned a, unsigned b) { return a < b ? a : b; }

__device__ __forceinline__ f16x8 loadA32(const float* p) {
    float4 a = *(const float4*)p, b = *(const float4*)(p + 4);
    F16U r;
    r.e[0]=(_Float16)a.x; r.e[1]=(_Float16)a.y; r.e[2]=(_Float16)a.z; r.e[3]=(_Float16)a.w;
    r.e[4]=(_Float16)b.x; r.e[5]=(_Float16)b.y; r.e[6]=(_Float16)b.z; r.e[7]=(_Float16)b.w;
    return r.v;
}

#define MFMA16(a, b, c) __builtin_amdgcn_mfma_f32_16x16x32_f16((a), (b), (c), 0, 0, 0)
#define BIDX(g, kc)  (((g) * 16 + lj) * 96 + ((((kc) * 4) + lq) ^ vg[(g)]))

// Issue 16 x-loads for 16 rows x full K=256 (fire-and-forget).
__device__ __forceinline__ void issue_x(const float* x_t, int arow, int lq, float4* xpf) {
    const float* xb = x_t + (size_t)arow * 256 + lq * 8;
#pragma unroll
    for (int i = 0; i < 8; ++i) {
        asm volatile("global_load_dwordx4 %0, %1, off offset:%c2"
                     : "=v"(xpf[2 * i]) : "v"(xb), "i"(i * 128));
        asm volatile("global_load_dwordx4 %0, %1, off offset:%c2"
                     : "=v"(xpf[2 * i + 1]) : "v"(xb), "i"(i * 128 + 16));
    }
}

// x-part of gates GEMM from prefetched registers: kc = 0..7 (K 0..255).
__device__ __forceinline__ void gemm_x_reg(const float4* xpf, const f16x8* Wl,
    int lj, int lq, const int* vg,
    f32x4& acc0, f32x4& acc1, f32x4& acc2, f32x4& acc3)
{
    asm volatile("s_waitcnt vmcnt(0)" ::: "memory");
    __builtin_amdgcn_sched_barrier(0);
#pragma unroll
    for (int kc = 0; kc < 8; ++kc) {
        float4 a = xpf[2 * kc], b = xpf[2 * kc + 1];
        F16U r;
        r.e[0]=(_Float16)a.x; r.e[1]=(_Float16)a.y; r.e[2]=(_Float16)a.z; r.e[3]=(_Float16)a.w;
        r.e[4]=(_Float16)b.x; r.e[5]=(_Float16)b.y; r.e[6]=(_Float16)b.z; r.e[7]=(_Float16)b.w;
        acc0 = MFMA16(r.v, Wl[BIDX(0, kc)], acc0);
        acc1 = MFMA16(r.v, Wl[BIDX(1, kc)], acc1);
        acc2 = MFMA16(r.v, Wl[BIDX(2, kc)], acc2);
        acc3 = MFMA16(r.v, Wl[BIDX(3, kc)], acc3);
    }
}

// Poll group's 32 producer blocks (4 wave-flags each). sc0 sc1 REQUIRED.
__device__ __forceinline__ void wait_flags(const uint4* fbase, int l, unsigned target) {
    if (l < 32) {
        const uint4* p = fbase + l;
        unsigned m;
        do {
            uint4 v;
            asm volatile("global_load_dwordx4 %0, %1, off sc0 sc1" : "=v"(v) : "v"(p));
            asm volatile("s_waitcnt vmcnt(0)" ::: "memory");
            m = umin_(umin_(v.x, v.y), umin_(v.z, v.w));
        } while (m < target);
    }
    __builtin_amdgcn_sched_barrier(0);
}

// h-part of gates GEMM (plain loads, write-once history buffer). Also issues
// the 2 attn loads (left in flight; retired by the epilogue's vmcnt(16)).
__device__ __forceinline__ void gemm_h_fb(const unsigned short* hsrc, const f16x8* Wl,
    int arow, int lj, int lq, const int* vg,
    const unsigned short* ap_dot, const unsigned short* ap_ctx,
    uint4& hdot, uint2& hctx,
    f32x4& acc0, f32x4& acc1, f32x4& acc2, f32x4& acc3)
{
    const unsigned short* hp = hsrc + (size_t)arow * 512 + lq * 8;
    s16x8 hf[16];
#pragma unroll
    for (int i = 0; i < 16; ++i)
        asm volatile("global_load_dwordx4 %0, %1, off offset:%c2"
                     : "=v"(hf[i]) : "v"(hp), "i"(i * 64));
    asm volatile("global_load_dwordx4 %0, %1, off" : "=v"(hdot) : "v"(ap_dot));
    asm volatile("global_load_dwordx2 %0, %1, off" : "=v"(hctx) : "v"(ap_ctx));

    asm volatile("s_waitcnt vmcnt(10)" ::: "memory");
    __builtin_amdgcn_sched_barrier(0);
#pragma unroll
    for (int kc = 8; kc < 16; ++kc) {
        f16x8 a = __builtin_bit_cast(f16x8, hf[kc - 8]);
        acc0 = MFMA16(a, Wl[BIDX(0, kc)], acc0);
        acc1 = MFMA16(a, Wl[BIDX(1, kc)], acc1);
        acc2 = MFMA16(a, Wl[BIDX(2, kc)], acc2);
        acc3 = MFMA16(a, Wl[BIDX(3, kc)], acc3);
    }
    asm volatile("s_waitcnt vmcnt(2)" ::: "memory");
    __builtin_amdgcn_sched_barrier(0);
#pragma unroll
    for (int kc = 16; kc < 24; ++kc) {
        f16x8 a = __builtin_bit_cast(f16x8, hf[kc - 8]);
        acc0 = MFMA16(a, Wl[BIDX(0, kc)], acc0);
        acc1 = MFMA16(a, Wl[BIDX(1, kc)], acc1);
        acc2 = MFMA16(a, Wl[BIDX(2, kc)], acc2);
        acc3 = MFMA16(a, Wl[BIDX(3, kc)], acc3);
    }
    // hdot/hctx intentionally left in flight.
}

// h-part from fp32 hidden_init (t=0 only).
__device__ __forceinline__ void gemm_h_init_fb(const float* hsrc, const f16x8* Wl,
    int arow, int lj, int lq, const int* vg,
    f32x4& acc0, f32x4& acc1, f32x4& acc2, f32x4& acc3)
{
    const float* hb = hsrc + (size_t)arow * 512 + lq * 8;
#pragma unroll
    for (int kc = 8; kc < 24; ++kc) {
        f16x8 a = loadA32(hb + (kc - 8) * 32);
        acc0 = MFMA16(a, Wl[BIDX(0, kc)], acc0);
        acc1 = MFMA16(a, Wl[BIDX(1, kc)], acc1);
        acc2 = MFMA16(a, Wl[BIDX(2, kc)], acc2);
        acc3 = MFMA16(a, Wl[BIDX(3, kc)], acc3);
    }
}

// Pure-register online-softmax update: each wave owns one attention row
// (row = attr0 + (w>>1)); computes the FULL 512-dot redundantly per wave
// and updates its 4 ctx cols (cols (w&1)*256 + l*4). No LDS, no barriers.
__device__ __forceinline__ void attn_apply(uint4 hd, uint2 hc, const float* wv8,
    float s_bias, float& m_r, float& l_r, float ctx[4])
{
    float p = h2f((unsigned short)(hd.x & 0xffffu)) * wv8[0]
            + h2f((unsigned short)(hd.x >> 16))     * wv8[1]
            + h2f((unsigned short)(hd.y & 0xffffu)) * wv8[2]
            + h2f((unsigned short)(hd.y >> 16))     * wv8[3]
            + h2f((unsigned short)(hd.z & 0xffffu)) * wv8[4]
            + h2f((unsigned short)(hd.z >> 16))     * wv8[5]
            + h2f((unsigned short)(hd.w & 0xffffu)) * wv8[6]
            + h2f((unsigned short)(hd.w >> 16))     * wv8[7];
#pragma unroll
    for (int off = 32; off > 0; off >>= 1) p += __shfl_xor(p, off);
    float s = p + s_bias;
    float m_new = fmaxf(m_r, s);
    float scale = __expf(m_r - m_new);   // exp(-inf)=0 on first update
    float pr    = __expf(s - m_new);
    ctx[0] = ctx[0] * scale + pr * h2f((unsigned short)(hc.x & 0xffffu));
    ctx[1] = ctx[1] * scale + pr * h2f((unsigned short)(hc.x >> 16));
    ctx[2] = ctx[2] * scale + pr * h2f((unsigned short)(hc.y & 0xffffu));
    ctx[3] = ctx[3] * scale + pr * h2f((unsigned short)(hc.y >> 16));
    l_r = l_r * scale + pr;
    m_r = m_new;
}

#define SMEM_FB 104192

__global__ __launch_bounds__(256, 1) void lstm_hist(
    const float* __restrict__ xg,
    const float* __restrict__ hinit, const float* __restrict__ cinit,
    const float* __restrict__ W_ih, const float* __restrict__ W_hh,
    const float* __restrict__ b_ih, const float* __restrict__ b_hh,
    const float* __restrict__ attn_w, const float* __restrict__ attn_b,
    const float* __restrict__ W1, const float* __restrict__ b1,
    const float* __restrict__ W2, const float* __restrict__ b2,
    const float* __restrict__ W3, const float* __restrict__ b3,
    const float* __restrict__ W4, const float* __restrict__ b4,
    float* __restrict__ out,
    unsigned short* __restrict__ hbA, unsigned* __restrict__ flags)
{
    extern __shared__ char smem[];
    f16x8* Wl    = (f16x8*)smem;
    float* bsum  = (float*)(smem + 98304);
    float* xmlp  = (float*)(smem + 98304 + 512);
    float* x1s   = xmlp + 1024;
    float* x2s   = x1s + 128;
    float* x3s   = x2s + 128;

    const int tid = threadIdx.x, bid = blockIdx.x;
    const int mt = bid & 7, nt = bid >> 3;
    const int hc0 = nt * 16;
    const int w = tid >> 6, l = tid & 63;
    const int lj = l & 15, lq = l >> 4;

    int vg[4];
#pragma unroll
    for (int g = 0; g < 4; ++g) {
        int q = g * 16 + lj;
        vg[g] = ((q >> 3) ^ q) & 7;
    }

    // ---- stage W into LDS (f16, gate-interleaved, row-dependent XOR swizzle) ----
    {
        int q = tid >> 2, si = tid & 3;
        int vq = ((q >> 3) ^ q) & 7;
        int grow = (q >> 4) * 512 + hc0 + (q & 15);
        const float* ih = W_ih + (size_t)grow * 256;
        const float* hh = W_hh + (size_t)grow * 512;
        for (int cc = 0; cc < 24; ++cc) {
            int s = si * 24 + cc;
            int k0 = s * 8;
            const float* p = (k0 < 256) ? (ih + k0) : (hh + (k0 - 256));
            Wl[q * 96 + (s ^ vq)] = loadA32(p);
        }
        if (tid < 64) {
            int gr = (tid >> 4) * 512 + hc0 + (tid & 15);
            bsum[tid] = b_ih[gr] + b_hh[gr];
        }
    }
    __syncthreads();

    const int arow = mt * 64 + w * 16 + lj;
    const int crow = mt * 64 + w * 16 + lq * 4;
    const int ccol = hc0 + lj;
    float creg[4];
#pragma unroll
    for (int r = 0; r < 4; ++r)
        creg[r] = cinit[(size_t)(crow + r) * 512 + ccol];

    // attention state: thread-private (redundant per wave-pair, consistent)
    float m_r = -__builtin_inff(), l_r = 0.f;
    float ctx[4] = {0.f, 0.f, 0.f, 0.f};
    uint4 hdot = {0, 0, 0, 0}; uint2 hctx = {0, 0};
    const int attr0 = mt * 64 + nt * 2;
    const int arow_at = attr0 + (w >> 1);
    const float s_bias = attn_b[0];
    float wv8[8];
    {
        float4 a = *(const float4*)(attn_w + l * 8);
        float4 b = *(const float4*)(attn_w + l * 8 + 4);
        wv8[0]=a.x; wv8[1]=a.y; wv8[2]=a.z; wv8[3]=a.w;
        wv8[4]=b.x; wv8[5]=b.y; wv8[6]=b.z; wv8[7]=b.w;
    }
    float bs0 = bsum[lj], bs1 = bsum[16 + lj], bs2 = bsum[32 + lj], bs3 = bsum[48 + lj];

    const size_t aoff_dot = (size_t)arow_at * 512 + l * 8;
    const size_t aoff_ctx = (size_t)arow_at * 512 + (w & 1) * 256 + l * 4;
    const uint4* fbase = (const uint4*)flags + mt * 32;
    unsigned* myflag = flags + (size_t)(mt * 32 + nt) * 4 + w;

    float4 xpf[16];
    issue_x(xg, arow, lq, xpf);

    for (int t = 0; t < 256; ++t) {
        unsigned short* hb_cur = hbA + (size_t)t * 262144;
        const unsigned short* hb_prev = hb_cur - 262144;

        f32x4 acc0 = {0,0,0,0}, acc1 = {0,0,0,0}, acc2 = {0,0,0,0}, acc3 = {0,0,0,0};
        gemm_x_reg(xpf, Wl, lj, lq, vg, acc0, acc1, acc2, acc3);

        if (t >= 2) attn_apply(hdot, hctx, wv8, s_bias, m_r, l_r, ctx);

        if (t > 0) {
            wait_flags(fbase, l, (unsigned)t);
            gemm_h_fb(hb_prev, Wl, arow, lj, lq, vg,
                      hb_prev + aoff_dot, hb_prev + aoff_ctx, hdot, hctx,
                      acc0, acc1, acc2, acc3);
        } else {
            gemm_h_init_fb(hinit, Wl, arow, lj, lq, vg, acc0, acc1, acc2, acc3);
        }

#pragma unroll
        for (int r = 0; r < 4; ++r) {
            float ii = sigf(acc0[r] + bs0);
            float ff = sigf(acc1[r] + bs1);
            float gt = tanh_(acc2[r] + bs2);
            float oo = sigf(acc3[r] + bs3);
            float cn = ff * creg[r] + ii * gt;
            creg[r] = cn;
            float hv = oo * tanh_(cn);
            size_t off = (size_t)(crow + r) * 512 + ccol;
            unsigned short hvs = f2h(hv);
            unsigned short* sp = hb_cur + off;
            asm volatile("global_store_short %0, %1, off sc0 sc1"
                         :: "v"(sp), "v"(hvs) : "memory");
            if (t == 255) out[512 + off] = hv;
        }

        const float* xnext = xg + (size_t)(t < 255 ? t + 1 : 255) * 131072;
        issue_x(xnext, arow, lq, xpf);

        asm volatile("s_waitcnt vmcnt(16)" ::: "memory");
        if (l == 0) {
            unsigned fv = (unsigned)(t + 1);
            asm volatile("global_store_dword %0, %1, off sc0 sc1"
                         :: "v"(myflag), "v"(fv) : "memory");
        }
    }

    attn_apply(hdot, hctx, wv8, s_bias, m_r, l_r, ctx);
    wait_flags(fbase, l, 256u);
    {
        const unsigned short* hlast = hbA + (size_t)255 * 262144;
        const unsigned short* hp = hlast + aoff_dot;
        const unsigned short* hc = hlast + aoff_ctx;
        asm volatile("global_load_dwordx4 %0, %1, off" : "=v"(hdot) : "v"(hp));
        asm volatile("global_load_dwordx2 %0, %1, off" : "=v"(hctx) : "v"(hc));
        asm volatile("s_waitcnt vmcnt(0)" ::: "memory");
        __builtin_amdgcn_sched_barrier(0);
        attn_apply(hdot, hctx, wv8, s_bias, m_r, l_r, ctx);
    }

    // cT copyout
#pragma unroll
    for (int r = 0; r < 4; ++r)
        out[512 + 262144 + (size_t)(crow + r) * 512 + ccol] = creg[r];

    // ---- fused output MLP for this block's 2 batch rows ----
    {
        float linv = 1.0f / l_r;
        int row = tid >> 7, coff = (tid & 127) * 4;
#pragma unroll
        for (int i = 0; i < 4; ++i) xmlp[row * 512 + coff + i] = ctx[i] * linv;
    }
    __syncthreads();
    if (tid < 128) {
        int r = tid >> 6, f = tid & 63;
        const float* wp = W1 + (size_t)f * 512;
        const float* xp = xmlp + r * 512;
        float a = b1[f];
        for (int j = 0; j < 512; ++j) a = fmaf(xp[j], wp[j], a);
        x1s[r * 64 + f] = tanh_(a);
    }
    __syncthreads();
    if (tid < 128) {
        int r = tid >> 6, f = tid & 63;
        const float* wp = W2 + f * 64;
        const float* xp = x1s + r * 64;
        float a = b2[f];
        for (int j = 0; j < 64; ++j) a = fmaf(xp[j], wp[j], a);
        x2s[r * 64 + f] = tanh_(a);
    }
    __syncthreads();
    if (tid < 64) {
        int r = tid >> 5, f = tid & 31;
        const float* wp = W3 + f * 64;
        const float* xp = x2s + r * 64;
        float a = b3[f];
        for (int j = 0; j < 64; ++j) a = fmaf(xp[j], wp[j], a);
        x3s[r * 32 + f] = tanh_(a);
    }
    __syncthreads();
    if (tid < 2) {
        const float* xp = x3s + tid * 32;
        float a = b4[0];
        for (int j = 0; j < 32; ++j) a = fmaf(xp[j], W4[j], a);
        out[attr0 + tid] = a;
    }
}

extern "C" void kernel_launch(void* const* d_in, const int* in_sizes, int n_in,
                              void* d_out, int out_size, void* d_ws, size_t ws_size,
                              hipStream_t stream) {
    const float* xg     = (const float*)d_in[0];
    const float* hinit  = (const float*)d_in[1];
    const float* cinit  = (const float*)d_in[2];
    const float* W_ih   = (const float*)d_in[3];
    const float* W_hh   = (const float*)d_in[4];
    const float* b_ih   = (const float*)d_in[5];
    const float* b_hh   = (const float*)d_in[6];
    const float* attn_w = (const float*)d_in[7];
    const float* attn_b = (const float*)d_in[8];
    const float* W1 = (const float*)d_in[9],  *b1 = (const float*)d_in[10];
    const float* W2 = (const float*)d_in[11], *b2 = (const float*)d_in[12];
    const float* W3 = (const float*)d_in[13], *b3 = (const float*)d_in[14];
    const float* W4 = (const float*)d_in[15], *b4 = (const float*)d_in[16];

    const size_t HS_BYTES = 134217728ull;   // 256*512*512 f16 history

    unsigned short* hs = (unsigned short*)d_ws;
    unsigned* flags = (unsigned*)((char*)d_ws + HS_BYTES);
    hipMemsetAsync(flags, 0, 4096, stream);
    hipFuncSetAttribute((const void*)lstm_hist,
                        hipFuncAttributeMaxDynamicSharedMemorySize, SMEM_FB);
    lstm_hist<<<256, 256, SMEM_FB, stream>>>(
        xg, hinit, cinit, W_ih, W_hh, b_ih, b_hh, attn_w, attn_b,
        W1, b1, W2, b2, W3, b3, W4, b4,
        (float*)d_out, hs, flags);
}